// Round 3
// baseline (900.153 us; speedup 1.0000x reference)
//
#include <hip/hip_runtime.h>
#include <hip/hip_cooperative_groups.h>

namespace cg = cooperative_groups;

// ActiveParticles forward pass, N=4096, float32. Single cooperative kernel.
#define NPART 4096
#define PI_F 3.1415927410125732f
#define TWO_PI_F 6.2831854820251465f

__device__ __forceinline__ float wrapf(float d) {
    // replicates: d = where(d <= -PI, mod(d, PI), d); d -= (d >= PI)*2PI
    if (d <= -PI_F) {
        d = fmodf(d, PI_F);
        if (d < 0.0f) d += PI_F;     // python-mod sign fixup
    }
    if (d >= PI_F) d -= TWO_PI_F;
    return d;
}

// 256 blocks x 512 threads, cooperative. Block owns 16 particles (li = tid&15),
// 32 j-slices (sl = tid>>4).
__global__ __launch_bounds__(512)
void k_fused(const float* __restrict__ pr, const float* __restrict__ pim,
             const float* __restrict__ orr, const float* __restrict__ oim,
             const float* __restrict__ deltas,
             const float* __restrict__ rot_noise,
             const float* __restrict__ tn_re, const float* __restrict__ tn_im,
             float* __restrict__ out,
             float2* __restrict__ pA, float2* __restrict__ pB,
             int* __restrict__ cnt) {
    __shared__ __align__(16) float smem[8192];       // 32 KB, aliased per phase
    float4* ls4 = (float4*)smem;                     // phase A: 512 x (pr,pim,or,oi)
    float2* lsp = (float2*)smem;                     // phase B: 4096 positions
    __shared__ float red0[512], red1[512], red2[512], red3[512], red4[512];
    __shared__ float cr_[512], ci_[512];
    __shared__ int   rc_[512];

    cg::grid_group grid = cg::this_grid();
    int tid = threadIdx.x;
    int li = tid & 15, sl = tid >> 4;                // sl in 0..31
    int i = blockIdx.x * 16 + li;
    float2* o2 = (float2*)out;

    // ================= Phase A: interaction pass =================
    {
        constexpr float RR_F  = 8e-6f;
        constexpr float RR2   = RR_F * RR_F;
        constexpr float ROC_F = (float)(2.5e-5 + 3.15e-6);   // RO + RC
        constexpr float ROC2  = ROC_F * ROC_F;

        float px = pr[i], py = pim[i];
        float ox = orr[i], oy = oim[i];

        float n_r = 0.0f, S_re = 0.0f, S_im = 0.0f, o_re = 0.0f, o_im = 0.0f;
        float cs_re = 0.0f, cs_im = 0.0f;

        for (int c = 0; c < 8; ++c) {
            int j0 = c * 512;
            __syncthreads();
            float jr = pr[j0 + tid], ji = pim[j0 + tid];
            ls4[tid] = make_float4(jr, ji, orr[j0 + tid], oim[j0 + tid]);
            cs_re += jr; cs_im += ji;                // each j staged exactly once
            __syncthreads();
#pragma unroll
            for (int t = 0; t < 16; ++t) {
                int jj = sl * 16 + ((t + 2 * sl) & 15);   // bank-swizzled
                int j = j0 + jj;
                float4 v = ls4[jj];
                float dr = px - v.x;
                float di = py - v.y;
                float d2 = dr * dr + di * di;
                bool wro = d2 <= ROC2;                    // self included (d2=0)
                float dot = ox * v.z + oy * v.w;          // in-front: cos(ai-aj)>0
                bool wrr = (d2 <= RR2) & (dot > 0.0f) & (j != i);
                if (wro) { o_re += v.z; o_im += v.w; }
                if (wrr) { n_r += 1.0f; S_re += v.x; S_im += v.y; }
            }
        }

        red0[tid] = n_r; red1[tid] = S_re; red2[tid] = S_im;
        red3[tid] = o_re; red4[tid] = o_im;
        cr_[tid] = cs_re; ci_[tid] = cs_im;
        __syncthreads();
        for (int s = 256; s > 0; s >>= 1) {              // cms tree-reduce
            if (tid < s) { cr_[tid] += cr_[tid + s]; ci_[tid] += ci_[tid + s]; }
            __syncthreads();
        }

        if (tid < 16) {   // per-particle epilogue (li == tid)
#pragma unroll
            for (int s = 1; s < 32; ++s) {
                int t2 = (s << 4) | tid;
                n_r += red0[t2]; S_re += red1[t2]; S_im += red2[t2];
                o_re += red3[t2]; o_im += red4[t2];
            }
            float maxnr = fmaxf(n_r, 1.0f);
            float sgn = (n_r > 0.0f) ? 1.0f : 0.0f;
            float Sre = S_re / maxnr - px * sgn;
            float Sim = S_im / maxnr - py * sgn;
            float d_re = -Sre, d_im = -Sim;

            float cmsx = cr_[0] * (1.0f / 4096.0f);
            float cmsy = ci_[0] * (1.0f / 4096.0f);
            float Ps_re = cmsx - px;                     // n_a = 4096 > 0
            float Ps_im = cmsy - py;

            float dl = deltas[i];
            float cd = cosf(dl), sd = sinf(dl);
            float l_re = Ps_re * cd - Ps_im * sd;        // Ps * e^{+i d}
            float l_im = Ps_re * sd + Ps_im * cd;
            float r_re = Ps_re * cd + Ps_im * sd;        // Ps * e^{-i d}
            float r_im = Ps_im * cd - Ps_re * sd;

            float nb   = fmaxf(hypotf(o_re, o_im), 1e-14f);
            float na_l = fmaxf(hypotf(l_re, l_im), 1e-14f);
            float na_r = fmaxf(hypotf(r_re, r_im), 1e-14f);
            float csl = (l_re * o_re + l_im * o_im) / (na_l * nb);
            float csr = (r_re * o_re + r_im * o_im) / (na_r * nb);
            float b_re = (csl >= csr) ? l_re : r_re;
            float b_im = (csl >= csr) ? l_im : r_im;

            float ai = atan2f(oy, ox);
            bool has_rep = (d_re != 0.0f) || (d_im != 0.0f);
            float att;
            if (has_rep) att = wrapf(atan2f(d_im, d_re) - ai);
            else         att = wrapf(atan2f(b_im, b_re) - ai);

            constexpr float GDD  = (float)(0.2 * 25.0 * 0.0028);  // DT*GAMMA*DR
            constexpr float S2DR = 0.07483314773547883f;           // sqrt(2*DR)
            constexpr float SDT  = 0.44721359549995793f;           // sqrt(DT)
            float theta = GDD * sinf(att) + (rot_noise[i] * S2DR) * SDT;
            float rr_ = cosf(theta), ri_ = sinf(theta);

            float no_re = ox * rr_ - oy * ri_;
            float no_im = ox * ri_ + oy * rr_;

            constexpr float DTVEL = (float)(0.2 * 5e-7);
            constexpr float C1 = 0.70710678118654752f;             // sqrt(0.5)
            constexpr float C2 = 1.6733200530681511e-07f;          // sqrt(2*DT_TRANS)
            float t_re = DTVEL * ox + ((tn_re[i] * C1) * C2) * SDT;
            float t_im = DTVEL * oy + ((tn_im[i] * C1) * C2) * SDT;
            pA[i] = make_float2(px + t_re, py + t_im);

            o2[1 * 4096 + i] = make_float2(no_re, no_im);
            o2[2 * 4096 + i] = make_float2(o_re, o_im);
            o2[3 * 4096 + i] = make_float2(l_re, l_im);
            o2[4 * 4096 + i] = make_float2(r_re, r_im);
        }
    }

    // zero the per-iteration collision counters (d_ws is poisoned 0xAA)
    if (blockIdx.x == 0 && tid < 32) cnt[tid] = 0;
    __threadfence();
    grid.sync();

    // ================= Phase B: collision loop =================
    {
        constexpr float TWO_RC  = (float)(2.0 * 3.15e-6);
        constexpr float TWO_RC2 = TWO_RC * TWO_RC;
        constexpr float C21RC   = (float)(2.1 * 3.15e-6);

        float2* cur = pA;
        float2* nxt = pB;
        float2 npf = make_float2(0.0f, 0.0f);

        for (int it = 0; it < 30; ++it) {
            __syncthreads();                     // protect lsp reuse
#pragma unroll
            for (int c = 0; c < 8; ++c) lsp[tid + 512 * c] = cur[tid + 512 * c];
            __syncthreads();

            float2 p = lsp[i];
            float mre = 0.0f, mim = 0.0f;
            int nc = 0;
#pragma unroll 8
            for (int t = 0; t < 128; ++t) {
                int jj = t * 32 + sl;            // conflict-free: 4 distinct banks/wave
                float2 q = lsp[jj];
                float dr = q.x - p.x;            // diff = p_j - p_i
                float di = q.y - p.y;
                float d2 = dr * dr + di * di;
                if (d2 <= TWO_RC2 && jj != i) {
                    float a = sqrtf(d2);
                    float m = (C21RC - a) * 0.5f / a;
                    mre += dr * m; mim += di * m; ++nc;
                }
            }

            red0[tid] = mre; red1[tid] = mim; rc_[tid] = nc;
            __syncthreads();
            if (tid < 16) {
#pragma unroll
                for (int s = 1; s < 32; ++s) {
                    int t2 = (s << 4) | tid;
                    mre += red0[t2]; mim += red1[t2]; nc += rc_[t2];
                }
                float2 np = make_float2(p.x - mre, p.y - mim);
                nxt[i] = np;
                npf = np;
                rc_[tid] = nc;                   // per-i totals into [0..15]
            }
            __syncthreads();
            if (tid == 0) {
                int tot = 0;
#pragma unroll
                for (int s = 0; s < 16; ++s) tot += rc_[s];
                if (tot > 0) atomicAdd(&cnt[it], tot);
            }
            __threadfence();
            grid.sync();
            int total = __hip_atomic_load(&cnt[it], __ATOMIC_ACQUIRE,
                                          __HIP_MEMORY_SCOPE_AGENT);
            float2* tmp = cur; cur = nxt; nxt = tmp;
            if (total == 0) break;               // uniform across the grid
        }

        if (tid < 16) o2[i] = npf;               // final positions
    }
}

extern "C" void kernel_launch(void* const* d_in, const int* in_sizes, int n_in,
                              void* d_out, int out_size, void* d_ws, size_t ws_size,
                              hipStream_t stream) {
    const float* pos_re = (const float*)d_in[0];
    const float* pos_im = (const float*)d_in[1];
    const float* ori_re = (const float*)d_in[2];
    const float* ori_im = (const float*)d_in[3];
    const float* deltas = (const float*)d_in[4];
    const float* rot_noise = (const float*)d_in[5];
    const float* tn_re = (const float*)d_in[6];
    const float* tn_im = (const float*)d_in[7];
    float* out = (float*)d_out;

    float2* pA = (float2*)d_ws;          // N
    float2* pB = pA + NPART;             // N
    int* cnt = (int*)(pB + NPART);       // 32 per-iteration collision counters

    void* args[] = {(void*)&pos_re, (void*)&pos_im, (void*)&ori_re, (void*)&ori_im,
                    (void*)&deltas, (void*)&rot_noise, (void*)&tn_re, (void*)&tn_im,
                    (void*)&out, (void*)&pA, (void*)&pB, (void*)&cnt};
    hipLaunchCooperativeKernel((void*)k_fused, dim3(256), dim3(512), args, 0, stream);
}

// Round 4
// 150.333 us; speedup vs baseline: 5.9877x; 5.9877x over previous
//
#include <hip/hip_runtime.h>

// ActiveParticles forward pass, N=4096, float32.
// K1: N^2 interaction pass + neighbor-candidate list (cutoff 2Rc+8um on
//     ORIGINAL positions — provable superset of collision pairs, since
//     trans <= 0.35um and collision drift << 7.5um budget).
// K2: single-workgroup collision loop over the sparse candidate lists,
//     positions resident in LDS, __syncthreads instead of grid sync.
#define NPART 4096
#define PI_F 3.1415927410125732f
#define TWO_PI_F 6.2831854820251465f

__device__ __forceinline__ float wrapf(float d) {
    // replicates: d = where(d <= -PI, mod(d, PI), d); d -= (d >= PI)*2PI
    if (d <= -PI_F) {
        d = fmodf(d, PI_F);
        if (d < 0.0f) d += PI_F;     // python-mod sign fixup
    }
    if (d >= PI_F) d -= TWO_PI_F;
    return d;
}

// ---------------- K1: interaction pass + neighbor build ----------------
// 512 blocks x 512 threads; block owns 8 i's (li=tid&7), 64 j-slices of 8.
__global__ __launch_bounds__(512, 4)
void k_interact(const float* __restrict__ pr, const float* __restrict__ pim,
                const float* __restrict__ orr, const float* __restrict__ oim,
                const float* __restrict__ deltas,
                const float* __restrict__ rot_noise,
                const float* __restrict__ tn_re, const float* __restrict__ tn_im,
                float* __restrict__ out, float2* __restrict__ p0,
                int* __restrict__ nbrG, int* __restrict__ ncntG) {
    constexpr float RR_F  = 8e-6f;
    constexpr float RR2   = RR_F * RR_F;
    constexpr float ROC_F = (float)(2.5e-5 + 3.15e-6);   // RO + RC
    constexpr float ROC2  = ROC_F * ROC_F;
    constexpr float CUT_F = 14.3e-6f;                    // 2Rc + 8um candidate cutoff
    constexpr float CUT2  = CUT_F * CUT_F;

    __shared__ float4 ls4[512];                          // (pr,pim,or,oi) per j
    __shared__ float red0[512], red1[512], red2[512], red3[512], red4[512];
    __shared__ float cr_[512], ci_[512];
    __shared__ int ncnt[8];

    int tid = threadIdx.x;
    int li = tid & 7, sl = tid >> 3;                     // sl in 0..63
    int i = blockIdx.x * 8 + li;

    if (tid < 8) ncnt[tid] = 0;

    float px = pr[i], py = pim[i];
    float ox = orr[i], oy = oim[i];

    float n_r = 0.0f, S_re = 0.0f, S_im = 0.0f, o_re = 0.0f, o_im = 0.0f;
    float cs_re = 0.0f, cs_im = 0.0f;

    for (int c = 0; c < 8; ++c) {
        int j0 = c * 512;
        __syncthreads();
        float jr = pr[j0 + tid], ji = pim[j0 + tid];
        ls4[tid] = make_float4(jr, ji, orr[j0 + tid], oim[j0 + tid]);
        cs_re += jr; cs_im += ji;                        // each j staged exactly once
        __syncthreads();
#pragma unroll
        for (int t = 0; t < 8; ++t) {
            int jj = sl * 8 + ((t + sl) & 7);            // bank-swizzled: conflict-free
            int j = j0 + jj;
            float4 v = ls4[jj];
            float dr = px - v.x;
            float di = py - v.y;
            float d2 = dr * dr + di * di;
            bool wro = d2 <= ROC2;                       // self included (d2=0)
            float dot = ox * v.z + oy * v.w;             // in-front: cos(ai-aj)>0
            bool wrr = (d2 <= RR2) & (dot > 0.0f) & (j != i);
            if (wro) { o_re += v.z; o_im += v.w; }
            if (wrr) { n_r += 1.0f; S_re += v.x; S_im += v.y; }
            if (d2 <= CUT2 && j != i) {                  // neighbor candidate (rare)
                int slot = atomicAdd(&ncnt[li], 1);
                if (slot < 16) nbrG[i * 16 + slot] = j;
            }
        }
    }

    red0[tid] = n_r; red1[tid] = S_re; red2[tid] = S_im;
    red3[tid] = o_re; red4[tid] = o_im;
    cr_[tid] = cs_re; ci_[tid] = cs_im;
    __syncthreads();
    for (int s = 256; s > 0; s >>= 1) {                  // cms tree-reduce
        if (tid < s) { cr_[tid] += cr_[tid + s]; ci_[tid] += ci_[tid + s]; }
        __syncthreads();
    }

    if (tid < 8) {   // per-particle epilogue (li == tid)
        for (int s = 1; s < 64; ++s) {
            int t2 = (s << 3) | tid;
            n_r += red0[t2]; S_re += red1[t2]; S_im += red2[t2];
            o_re += red3[t2]; o_im += red4[t2];
        }
        ncntG[i] = min(ncnt[tid], 16);

        float maxnr = fmaxf(n_r, 1.0f);
        float sgn = (n_r > 0.0f) ? 1.0f : 0.0f;
        float Sre = S_re / maxnr - px * sgn;
        float Sim = S_im / maxnr - py * sgn;
        float d_re = -Sre, d_im = -Sim;

        float cmsx = cr_[0] * (1.0f / 4096.0f);
        float cmsy = ci_[0] * (1.0f / 4096.0f);
        float Ps_re = cmsx - px;                         // n_a = 4096 > 0
        float Ps_im = cmsy - py;

        float dl = deltas[i];
        float cd = cosf(dl), sd = sinf(dl);
        float l_re = Ps_re * cd - Ps_im * sd;            // Ps * e^{+i d}
        float l_im = Ps_re * sd + Ps_im * cd;
        float r_re = Ps_re * cd + Ps_im * sd;            // Ps * e^{-i d}
        float r_im = Ps_im * cd - Ps_re * sd;

        float nb   = fmaxf(hypotf(o_re, o_im), 1e-14f);
        float na_l = fmaxf(hypotf(l_re, l_im), 1e-14f);
        float na_r = fmaxf(hypotf(r_re, r_im), 1e-14f);
        float csl = (l_re * o_re + l_im * o_im) / (na_l * nb);
        float csr = (r_re * o_re + r_im * o_im) / (na_r * nb);
        float b_re = (csl >= csr) ? l_re : r_re;
        float b_im = (csl >= csr) ? l_im : r_im;

        float ai = atan2f(oy, ox);
        bool has_rep = (d_re != 0.0f) || (d_im != 0.0f);
        float att;
        if (has_rep) att = wrapf(atan2f(d_im, d_re) - ai);
        else         att = wrapf(atan2f(b_im, b_re) - ai);

        constexpr float GDD  = (float)(0.2 * 25.0 * 0.0028);  // DT*GAMMA*DR
        constexpr float S2DR = 0.07483314773547883f;           // sqrt(2*DR)
        constexpr float SDT  = 0.44721359549995793f;           // sqrt(DT)
        float theta = GDD * sinf(att) + (rot_noise[i] * S2DR) * SDT;
        float rr_ = cosf(theta), ri_ = sinf(theta);

        float no_re = ox * rr_ - oy * ri_;
        float no_im = ox * ri_ + oy * rr_;

        constexpr float DTVEL = (float)(0.2 * 5e-7);
        constexpr float C1 = 0.70710678118654752f;             // sqrt(0.5)
        constexpr float C2 = 1.6733200530681511e-07f;          // sqrt(2*DT_TRANS)
        float t_re = DTVEL * ox + ((tn_re[i] * C1) * C2) * SDT;
        float t_im = DTVEL * oy + ((tn_im[i] * C1) * C2) * SDT;
        p0[i] = make_float2(px + t_re, py + t_im);

        float2* o2 = (float2*)out;
        o2[1 * 4096 + i] = make_float2(no_re, no_im);
        o2[2 * 4096 + i] = make_float2(o_re, o_im);
        o2[3 * 4096 + i] = make_float2(l_re, l_im);
        o2[4 * 4096 + i] = make_float2(r_re, r_im);
    }
}

// ---------------- K2: collision loop, ONE workgroup, sparse lists ----------
__global__ __launch_bounds__(1024)
void k_coll_all(const float2* __restrict__ p0, const int* __restrict__ nbrG,
                const int* __restrict__ ncntG, float* __restrict__ out) {
    constexpr float TWO_RC  = (float)(2.0 * 3.15e-6);
    constexpr float TWO_RC2 = TWO_RC * TWO_RC;
    constexpr float C21RC   = (float)(2.1 * 3.15e-6);
    constexpr int   NBCAP   = 12288;

    __shared__ float2 pos[NPART];          // 32 KB — the only position copy
    __shared__ unsigned short nbrL[NBCAP]; // 24 KB compacted neighbor entries
    __shared__ int cursor;
    __shared__ int wsum[16];
    __shared__ int flag;

    int tid = threadIdx.x;
    if (tid == 0) cursor = 0;

    int myc[4], myoff[4];
#pragma unroll
    for (int k = 0; k < 4; ++k) {
        int i = tid + 1024 * k;
        pos[i] = p0[i];
        myc[k] = min(ncntG[i], 16);
        myoff[k] = 0;
    }
    __syncthreads();
    // compact (and sort, for deterministic summation order) into LDS
#pragma unroll
    for (int k = 0; k < 4; ++k) {
        int i = tid + 1024 * k;
        int c = myc[k];
        if (c > 0) {
            int off = atomicAdd(&cursor, c);
            if (off + c > NBCAP) { c = max(0, NBCAP - off); myc[k] = c; }
            myoff[k] = off;
            for (int m = 0; m < c; ++m) {
                int j = nbrG[i * 16 + m];
                int t = m;                              // insertion sort by j
                while (t > 0 && (int)nbrL[off + t - 1] > j) {
                    nbrL[off + t] = nbrL[off + t - 1]; --t;
                }
                nbrL[off + t] = (unsigned short)j;
            }
        }
    }
    __syncthreads();

    for (int it = 0; it < 30; ++it) {
        int nc = 0;
        float nx[4], ny[4];
#pragma unroll
        for (int k = 0; k < 4; ++k) {                   // read phase
            int i = tid + 1024 * k;
            int c = myc[k];
            if (c > 0) {
                float2 p = pos[i];
                float mre = 0.0f, mim = 0.0f;
                int off = myoff[k];
                for (int m = 0; m < c; ++m) {
                    float2 q = pos[nbrL[off + m]];
                    float dr = q.x - p.x;               // diff = p_j - p_i
                    float di = q.y - p.y;
                    float d2 = dr * dr + di * di;
                    if (d2 <= TWO_RC2) {
                        float a = sqrtf(d2);
                        float mm = (C21RC - a) * 0.5f / a;
                        mre += dr * mm; mim += di * mm; ++nc;
                    }
                }
                nx[k] = p.x - mre; ny[k] = p.y - mim;
            }
        }
        __syncthreads();                                // all reads done
#pragma unroll
        for (int k = 0; k < 4; ++k) {                   // write phase
            if (myc[k] > 0) pos[tid + 1024 * k] = make_float2(nx[k], ny[k]);
        }
#pragma unroll
        for (int m = 1; m <= 32; m <<= 1) nc += __shfl_xor(nc, m, 64);
        if ((tid & 63) == 0) wsum[tid >> 6] = nc;
        __syncthreads();                                // writes + wsum visible
        if (tid == 0) {
            int tot = 0;
#pragma unroll
            for (int w = 0; w < 16; ++w) tot += wsum[w];
            flag = tot;
        }
        __syncthreads();
        if (flag == 0) break;                           // uniform: do-while done
    }

    float2* o2 = (float2*)out;
#pragma unroll
    for (int k = 0; k < 4; ++k) {
        int i = tid + 1024 * k;
        o2[i] = pos[i];
    }
}

extern "C" void kernel_launch(void* const* d_in, const int* in_sizes, int n_in,
                              void* d_out, int out_size, void* d_ws, size_t ws_size,
                              hipStream_t stream) {
    const float* pos_re = (const float*)d_in[0];
    const float* pos_im = (const float*)d_in[1];
    const float* ori_re = (const float*)d_in[2];
    const float* ori_im = (const float*)d_in[3];
    const float* deltas = (const float*)d_in[4];
    const float* rot_noise = (const float*)d_in[5];
    const float* tn_re = (const float*)d_in[6];
    const float* tn_im = (const float*)d_in[7];
    float* out = (float*)d_out;

    float2* p0   = (float2*)d_ws;            // N post-trans positions
    int* ncntG   = (int*)(p0 + NPART);       // N neighbor counts
    int* nbrG    = ncntG + NPART;            // N*16 neighbor indices

    k_interact<<<512, 512, 0, stream>>>(pos_re, pos_im, ori_re, ori_im,
                                        deltas, rot_noise, tn_re, tn_im,
                                        out, p0, nbrG, ncntG);
    k_coll_all<<<1, 1024, 0, stream>>>(p0, nbrG, ncntG, out);
}